// Round 9
// baseline (77.519 us; speedup 1.0000x reference)
//
#include <hip/hip_runtime.h>

// AttentionConvFull: grouped 1x1 QKV + 5x5 per-channel local attention, FUSED.
// B=4, H=W=56, C=OC=256, G=8, Cg=32, K=5, pad=2.
//
// One kernel, one block per (batch, 8x8 tile, group), 256 threads
// (c = tid&31 channel, p0 = tid>>5 pixel column/slice).
//   Phase A: wq row -> 32 regs; q for 8 interior pixels (x rows via broadcast
//            global loads); wq dies. Then wk/wv -> 64 regs.
//   Phase B: k,v for 144 halo pixels -> LDS (x rows broadcast-loaded from
//            global; 32 lanes same address = 2 transactions/instr, L1/L3-hot).
//   Phase C: R6 row-streaming attention: each halo row's 5 k/v read once,
//            scattered into up to 5 pixels; native exp2 (q pre-scaled by
//            log2e) + rcp; single-pass softmax (logits bounded, f32-safe).
//
// Register-budget law (R1-R8): VGPR cap = 256/N for __launch_bounds__(256,N);
// no launch_bounds also caps at 64. Spill signature: VGPR_Count == cap AND
// WRITE_SIZE >> logical bytes. Phased weight liveness keeps peak ~110 < 128.
// Why fused: R8 showed split qkv latency-bound (44.7us, VALUBusy 15%) and
// the ws round-trip costs ~70MB of traffic + a dispatch.

constexpr int TB = 4, TH = 56, TW = 56, TC = 256;
constexpr int G  = 8, CG = 32, PAD = 2;
constexpr int TILE = 8;
constexpr int HT = TILE + 2 * PAD;   // 12
constexpr int NT = TH / TILE;        // 7
constexpr int NPIX_HALO = HT * HT;   // 144
constexpr float LOG2E = 1.44269504088896340736f;

__global__ __launch_bounds__(256, 2)
void fused_attn_conv_kernel(const float* __restrict__ x,
                            const float* __restrict__ wq,
                            const float* __restrict__ wk,
                            const float* __restrict__ wv,
                            const float* __restrict__ rel,
                            const float* __restrict__ qemb,
                            float* __restrict__ out) {
    __shared__ float ks[NPIX_HALO][CG];   // 18 KB
    __shared__ float vs[NPIX_HALO][CG];   // 18 KB

    const int bid  = blockIdx.x;
    const int g    = bid & 7;
    const int tile = bid >> 3;
    const int tj   = tile % NT;
    const int ti   = (tile / NT) % NT;
    const int b    = tile / (NT * NT);

    const int t  = threadIdx.x;
    const int c  = t & 31;
    const int p0 = t >> 5;

    const int oc = g * CG + c;           // global out-channel
    const int h0 = ti * TILE - PAD, w0 = tj * TILE - PAD;

    // ---- Phase A: q for this thread's 8 interior pixels (column p0).
    //      wq row lives only here (32 regs), then dies before wk/wv load.
    float qreg[8];
    {
        float wqr[CG];
        const float4* wqp = (const float4*)(wq + (size_t)oc * CG);
#pragma unroll
        for (int i = 0; i < CG / 4; ++i) {
            float4 a = wqp[i];
            wqr[4*i+0]=a.x; wqr[4*i+1]=a.y; wqr[4*i+2]=a.z; wqr[4*i+3]=a.w;
        }
        const float qe = qemb[oc];
#pragma unroll 1
        for (int ii = 0; ii < 8; ++ii) {
            const int gh = ti * TILE + ii, gw = tj * TILE + p0;
            const float4* xp = (const float4*)(x + (((size_t)b * TH + gh) * TW + gw) * TC + g * CG);
            float aq = qe;
#pragma unroll
            for (int i = 0; i < CG / 4; ++i) {
                const float4 xv = xp[i];   // broadcast: 32 lanes same address
                aq = fmaf(wqr[4*i+0], xv.x, aq);
                aq = fmaf(wqr[4*i+1], xv.y, aq);
                aq = fmaf(wqr[4*i+2], xv.z, aq);
                aq = fmaf(wqr[4*i+3], xv.w, aq);
            }
            qreg[ii] = aq * LOG2E;         // pre-scaled for exp2 softmax
        }
    }

    // ---- Phase B: k,v for 18 halo pixels per thread-slice -> LDS.
    {
        float wkr[CG], wvr[CG];
        const float4* wkp = (const float4*)(wk + (size_t)oc * CG);
        const float4* wvp = (const float4*)(wv + (size_t)oc * CG);
#pragma unroll
        for (int i = 0; i < CG / 4; ++i) {
            float4 bb = wkp[i], cc = wvp[i];
            wkr[4*i+0]=bb.x; wkr[4*i+1]=bb.y; wkr[4*i+2]=bb.z; wkr[4*i+3]=bb.w;
            wvr[4*i+0]=cc.x; wvr[4*i+1]=cc.y; wvr[4*i+2]=cc.z; wvr[4*i+3]=cc.w;
        }
#pragma unroll 1
        for (int it = 0; it < NPIX_HALO / 8; ++it) {
            const int hp = it * 8 + p0;
            const int hi = hp / HT, hj = hp % HT;
            const int gh = h0 + hi, gw = w0 + hj;
            float ak = 0.f, av = 0.f;
            if (gh >= 0 && gh < TH && gw >= 0 && gw < TW) {
                const float4* xp = (const float4*)(x + (((size_t)b * TH + gh) * TW + gw) * TC + g * CG);
#pragma unroll
                for (int i = 0; i < CG / 4; ++i) {
                    const float4 xv = xp[i];   // broadcast within half-wave
                    ak = fmaf(wkr[4*i+0], xv.x, ak); av = fmaf(wvr[4*i+0], xv.x, av);
                    ak = fmaf(wkr[4*i+1], xv.y, ak); av = fmaf(wvr[4*i+1], xv.y, av);
                    ak = fmaf(wkr[4*i+2], xv.z, ak); av = fmaf(wvr[4*i+2], xv.z, av);
                    ak = fmaf(wkr[4*i+3], xv.w, ak); av = fmaf(wvr[4*i+3], xv.w, av);
                }
            }
            ks[hp][c] = ak;    // OOB rows stay 0: matches zero-padded conv
            vs[hp][c] = av;
        }
    }

    // rel row for this channel (global, L2-hot; compiler-managed regs)
    const float* rp = rel + (size_t)oc * 25;
    float relr[25];
#pragma unroll
    for (int i = 0; i < 25; ++i) relr[i] = rp[i];

    __syncthreads();

    // ---- Phase C: row-streaming attention (R6 structure, proven).
    float s_[8], a_[8];
#pragma unroll
    for (int ii = 0; ii < 8; ++ii) { s_[ii] = 0.f; a_[ii] = 0.f; }

#pragma unroll
    for (int h = 0; h < HT; ++h) {
        float kr[5], vr[5];
#pragma unroll
        for (int j = 0; j < 5; ++j) {
            kr[j] = ks[h * HT + p0 + j][c];
            vr[j] = vs[h * HT + p0 + j][c];
        }
#pragma unroll
        for (int ii = 0; ii < 8; ++ii) {
            const int di = h - ii;               // compile-time after unroll
            if (di >= 0 && di < 5) {
                const float qv = qreg[ii];
#pragma unroll
                for (int j = 0; j < 5; ++j) {
                    const float e = __builtin_amdgcn_exp2f(qv * (kr[j] + relr[di * 5 + j]));
                    s_[ii] += e;
                    a_[ii] = fmaf(e, vr[j], a_[ii]);
                }
            }
        }
    }

#pragma unroll
    for (int ii = 0; ii < 8; ++ii) {
        const int gh = ti * TILE + ii, gw = tj * TILE + p0;
        out[(((size_t)b * TH + gh) * TW + gw) * TC + g * CG + c] =
            a_[ii] * __builtin_amdgcn_rcpf(s_[ii]);
    }
}

extern "C" void kernel_launch(void* const* d_in, const int* in_sizes, int n_in,
                              void* d_out, int out_size, void* d_ws, size_t ws_size,
                              hipStream_t stream) {
    const float* x    = (const float*)d_in[0];
    const float* wq   = (const float*)d_in[1];
    const float* wk   = (const float*)d_in[2];
    const float* wv   = (const float*)d_in[3];
    const float* rel  = (const float*)d_in[4];
    const float* qemb = (const float*)d_in[5];
    float* out = (float*)d_out;

    const int nblocks = TB * NT * NT * G;   // 4*7*7*8 = 1568
    hipLaunchKernelGGL(fused_attn_conv_kernel, dim3(nblocks), dim3(256), 0, stream,
                       x, wq, wk, wv, rel, qemb, out);
}